// Round 4
// baseline (404.201 us; speedup 1.0000x reference)
//
#include <hip/hip_runtime.h>
#include <math.h>

// Dynamic_Loss on MI355X.
// Shapes: logit/ema_prob [8,20,512,512] f32, real_labels [8,512,512] i32,
// ema_thresh/moving_prob_avg [20] f32. Output: scalar f32.
//
// Factorization: loss = sum_c (1-new_mpa[c]) * Lsum[c] / n_valid, where
// Lsum[c] = sum over valid pixels with ema-class c of (lse - logit[c]).
// One streaming pass accumulates 61 scalars; a tiny kernel finishes.
// ws layout (floats): [0..19] score sums, [20..39] counts, [40..59] loss sums,
// [60] valid count.
//
// Round 4: occupancy WITHOUT spills. Cross-round evidence: R2 (occ 79%,
// VGPR forced to 32, spilled 366 MB scratch) moved 3.4 TB/s request-side --
// 35% more than any other config; R0/R1/R3 all sit at ~20% occupancy and
// ~2.5 TB/s regardless of per-wave load depth (R3's structural 8-deep DMA
// pipeline changed nothing). => throughput scales with resident waves, and
// per-wave MLP is NOT the limiter. This round: 2 px/thread merged body
// (minimal live state: ~7 regs/px), 4096 blocks, __launch_bounds__(256,6)
// -> VGPR cap ~85 (vs spill-forcing 32), expect no scratch + >=24 waves/CU.
//
// Merged capture state (exact semantics, absmax 0.0 rounds 1-3):
//   esel/earg/xsel = for rl<15: running (ema max over c<15, argmax, logit
//   there); for rl>=15 or IGN: values captured at channel cap_ch. For
//   rl>=15 the captured logit serves BOTH the score gather and loss gather.

#define PASTC 15
#define NCC   20
#define IGN   255
#define HW2   262144          // 512*512 = 2^18
#define ALPHAF 0.99f

__global__ __launch_bounds__(256, 6) void dl_main(
    const float* __restrict__ logit,
    const float* __restrict__ ema,
    const float* __restrict__ thresh,
    const int*   __restrict__ real,
    float*       __restrict__ ws)
{
    __shared__ float s_acc[61];
    __shared__ float s_thr[NCC];
    const int tid = threadIdx.x;
    if (tid < 61) s_acc[tid] = 0.0f;
    if (tid < NCC) s_thr[tid] = thresh[tid];
    __syncthreads();

    const int t  = blockIdx.x * 256 + tid;
    const int p0 = t << 1;                       // 2 pixels per thread
    const int b  = p0 >> 18;                     // batch
    const int s  = p0 & (HW2 - 1);               // spatial offset
    const size_t base = (((size_t)(b * NCC)) << 18) + (size_t)s;
    const float* eb = ema   + base;
    const float* lb = logit + base;

    const int2 rl2 = *reinterpret_cast<const int2*>(real + p0);
    const int rl[2] = {rl2.x, rl2.y};

    int   cap_ch[2];               // -1: rl<15 (argmax path); else channel to capture
    float se[2], x_m15[2], esel[2], xsel[2];
    int   arg15[2], earg[2];
#pragma unroll
    for (int j = 0; j < 2; ++j) {
        cap_ch[j] = (rl[j] == IGN) ? 0 : (rl[j] >= PASTC ? rl[j] : -1);
        se[j] = 0.0f; x_m15[j] = -INFINITY; esel[j] = -INFINITY;
        xsel[j] = 0.0f; arg15[j] = 0; earg[j] = 0;
    }

    // ---------- merged single pass over 20 channels (compiler-scheduled) ----
#pragma unroll
    for (int c = 0; c < NCC; ++c) {
        const float2 ve = *reinterpret_cast<const float2*>(eb + ((size_t)c << 18));
        const float2 vl = *reinterpret_cast<const float2*>(lb + ((size_t)c << 18));
        const float ev[2] = {ve.x, ve.y};
        const float xv[2] = {vl.x, vl.y};
#pragma unroll
        for (int j = 0; j < 2; ++j) {
            const float x = xv[j];
            se[j] += __expf(x);
            if (c < PASTC) {
                const bool gl = x > x_m15[j];                 // first-max ties
                x_m15[j] = gl ? x : x_m15[j];
                arg15[j] = gl ? c : arg15[j];
            }
            const bool upd = (cap_ch[j] < 0)
                               ? (c < PASTC && ev[j] > esel[j])
                               : (c == cap_ch[j]);
            esel[j] = upd ? ev[j] : esel[j];
            earg[j] = upd ? c    : earg[j];
            xsel[j] = upd ? x    : xsel[j];
        }
    }

    // ---------- per-pixel epilogue -> LDS bins ----------
    float vcnt = 0.0f;
#pragma unroll
    for (int j = 0; j < 2; ++j) {
        const float lse = __logf(se[j]);             // ln(sum exp)
        if (rl[j] != IGN) {
            const int   lab  = (rl[j] >= PASTC) ? rl[j] : arg15[j];  // [0,19]
            const float sval = (rl[j] >= PASTC) ? xsel[j] : x_m15[j];
            const float prob = __expf(sval - lse);   // softmax prob at lab
            atomicAdd(&s_acc[lab], prob);
            atomicAdd(&s_acc[20 + lab], 1.0f);
        }
        const int  el    = (rl[j] >= PASTC) ? rl[j] : earg[j];  // 255 stays 255
        const float th   = s_thr[el < NCC ? el : (NCC - 1)];
        const bool valid = (el < NCC) && (esel[j] >= th);
        if (valid) {
            atomicAdd(&s_acc[40 + el], lse - xsel[j]);
        }
        const unsigned long long bm = __ballot(valid);
        if ((tid & 63) == 0) vcnt += (float)__popcll(bm);
    }
    if ((tid & 63) == 0) atomicAdd(&s_acc[60], vcnt);

    __syncthreads();
    if (tid < 61) atomicAdd(&ws[tid], s_acc[tid]);
}

__global__ void dl_final(const float* __restrict__ ws,
                         const float* __restrict__ mpa,
                         float*       __restrict__ out)
{
    if (threadIdx.x == 0 && blockIdx.x == 0) {
        float acc = 0.0f;
        for (int c = 0; c < NCC; ++c) {
            const float ssum = ws[c];
            const float cnt  = ws[20 + c];
            const float lsum = ws[40 + c];
            const float m    = mpa[c];
            const float mean = ssum / fmaxf(cnt, 1.0f);
            const float nm   = (cnt > 0.0f)
                                 ? ((m == -1.0f) ? mean
                                                 : (1.0f - ALPHAF) * mean + ALPHAF * m)
                                 : m;
            acc += lsum * (1.0f - nm);
        }
        out[0] = acc / ws[60];
    }
}

extern "C" void kernel_launch(void* const* d_in, const int* in_sizes, int n_in,
                              void* d_out, int out_size, void* d_ws, size_t ws_size,
                              hipStream_t stream) {
    const float* logit  = (const float*)d_in[0];
    const float* ema    = (const float*)d_in[1];
    const float* thresh = (const float*)d_in[2];
    const int*   real   = (const int*)d_in[3];
    const float* mpa    = (const float*)d_in[4];
    float* out = (float*)d_out;
    float* ws  = (float*)d_ws;

    // ws is re-poisoned to 0xAA before every timed launch; zero the 61 bins.
    hipMemsetAsync(ws, 0, 64 * sizeof(float), stream);

    // 2,097,152 pixels / 2 per thread / 256 per block = 4096 blocks (exact)
    dl_main<<<4096, 256, 0, stream>>>(logit, ema, thresh, real, ws);
    dl_final<<<1, 64, 0, stream>>>(ws, mpa, out);
}

// Round 5
// 382.343 us; speedup vs baseline: 1.0572x; 1.0572x over previous
//
#include <hip/hip_runtime.h>
#include <math.h>

// Dynamic_Loss on MI355X.
// Shapes: logit/ema_prob [8,20,512,512] f32, real_labels [8,512,512] i32,
// ema_thresh/moving_prob_avg [20] f32. Output: scalar f32.
//
// Factorization: loss = sum_c (1-new_mpa[c]) * Lsum[c] / n_valid, where
// Lsum[c] = sum over valid pixels with ema-class c of (lse - logit[c]).
// One streaming pass accumulates 61 scalars; a tiny kernel finishes.
// ws layout (floats): [0..19] score sums, [20..39] counts, [40..59] loss sums,
// [60] valid count.
//
// Round 5: burst-length theory. Cross-round table: throughput tracks DRAM
// burst length per channel-stream (4KB@2.67TB/s > 2KB@1.96TB/s) and stream
// count (split 20-stream passes beat merged 40-stream), and is INDIFFERENT
// to occupancy (19% beat 56%, R4) and per-wave load depth (R3 DMA null).
// => memory-side limit: 40 interleaved 1MB-strided streams with short
// bursts thrash HBM rows. This round: 16 px/thread (4 groups x float4),
// 512 blocks -> 16KB contiguous per channel per block (4x R0), and split
// ema/logit passes (20 streams at a time). After pass 1 the gather channel
// is KNOWN, so pass 2 captures via simple c==earg select.
//
// Semantics (absmax 0.0 lineage R1-R4):
//   esel/earg = for rl<15: running (ema max over c<15, argmax); for rl>=15:
//   (ema[rl], rl); for IGN: (ema[0], 0). xsel = logit at earg. For rl>=15
//   the captured logit serves BOTH the score gather and loss gather.

#define PASTC 15
#define NCC   20
#define IGN   255
#define HW2   262144          // 512*512 = 2^18
#define ALPHAF 0.99f
#define PPT   16              // pixels per thread
#define GRP   4               // groups of 4 (float4 each)

__global__ void dl_main(
    const float* __restrict__ logit,
    const float* __restrict__ ema,
    const float* __restrict__ thresh,
    const int*   __restrict__ real,
    float*       __restrict__ ws)
{
    __shared__ float s_acc[61];
    __shared__ float s_thr[NCC];
    const int tid = threadIdx.x;
    if (tid < 61) s_acc[tid] = 0.0f;
    if (tid < NCC) s_thr[tid] = thresh[tid];
    __syncthreads();

    const int P  = blockIdx.x * (256 * PPT);     // block pixel base (mult of 4096)
    const int b  = P >> 18;                      // batch (4096 divides 2^18)
    const int sp = P & (HW2 - 1);                // spatial base of block slab
    const size_t abase = (((size_t)(b * NCC)) << 18) + (size_t)sp;
    const int lo = tid << 2;                     // lane float4 offset in group

    // ---- real labels: 4 groups of int4 ----
    int rl[PPT];
#pragma unroll
    for (int g = 0; g < GRP; ++g) {
        const int4 r4 = *reinterpret_cast<const int4*>(real + P + g * 1024 + lo);
        rl[g*4+0] = r4.x; rl[g*4+1] = r4.y; rl[g*4+2] = r4.z; rl[g*4+3] = r4.w;
    }

    int   cap[PPT], earg[PPT];
    float esel[PPT];
#pragma unroll
    for (int j = 0; j < PPT; ++j) {
        cap[j]  = (rl[j] == IGN) ? 0 : (rl[j] >= PASTC ? rl[j] : -1);
        esel[j] = -INFINITY; earg[j] = 0;
    }

    // ---------- pass 1: ema, 20 streams, 16KB burst per channel ----------
    const float* eb = ema + abase;
#pragma unroll 3
    for (int c = 0; c < PASTC; ++c) {
        float4 v[GRP];
#pragma unroll
        for (int g = 0; g < GRP; ++g)
            v[g] = *reinterpret_cast<const float4*>(eb + ((size_t)c << 18) + g * 1024 + lo);
#pragma unroll
        for (int j = 0; j < PPT; ++j) {
            const float ev = ((const float*)&v[j >> 2])[j & 3];
            const bool upd = (cap[j] < 0) ? (ev > esel[j]) : (c == cap[j]);
            esel[j] = upd ? ev : esel[j];
            earg[j] = upd ? c  : earg[j];
        }
    }
#pragma unroll 1
    for (int c = PASTC; c < NCC; ++c) {          // capture-only channels
        float4 v[GRP];
#pragma unroll
        for (int g = 0; g < GRP; ++g)
            v[g] = *reinterpret_cast<const float4*>(eb + ((size_t)c << 18) + g * 1024 + lo);
#pragma unroll
        for (int j = 0; j < PPT; ++j) {
            const float ev = ((const float*)&v[j >> 2])[j & 3];
            const bool upd = (c == cap[j]);
            esel[j] = upd ? ev : esel[j];
            earg[j] = upd ? c  : earg[j];
        }
    }
    // earg now == gather channel for ALL pixels (rl<15: ema argmax;
    // rl>=15: rl; IGN: 0). cap[] is dead from here.

    // ---------- pass 2: logit, 20 streams ----------
    float se[PPT], x_m15[PPT], xsel[PPT];
    int   arg15[PPT];
#pragma unroll
    for (int j = 0; j < PPT; ++j) {
        se[j] = 0.0f; x_m15[j] = -INFINITY; xsel[j] = 0.0f; arg15[j] = 0;
    }
    const float* lb = logit + abase;
#pragma unroll 3
    for (int c = 0; c < PASTC; ++c) {
        float4 v[GRP];
#pragma unroll
        for (int g = 0; g < GRP; ++g)
            v[g] = *reinterpret_cast<const float4*>(lb + ((size_t)c << 18) + g * 1024 + lo);
#pragma unroll
        for (int j = 0; j < PPT; ++j) {
            const float x = ((const float*)&v[j >> 2])[j & 3];
            se[j] += __expf(x);
            const bool gl = x > x_m15[j];        // first-max ties (jnp.argmax)
            x_m15[j] = gl ? x : x_m15[j];
            arg15[j] = gl ? c : arg15[j];
            xsel[j]  = (c == earg[j]) ? x : xsel[j];
        }
    }
#pragma unroll 1
    for (int c = PASTC; c < NCC; ++c) {
        float4 v[GRP];
#pragma unroll
        for (int g = 0; g < GRP; ++g)
            v[g] = *reinterpret_cast<const float4*>(lb + ((size_t)c << 18) + g * 1024 + lo);
#pragma unroll
        for (int j = 0; j < PPT; ++j) {
            const float x = ((const float*)&v[j >> 2])[j & 3];
            se[j] += __expf(x);
            xsel[j] = (c == earg[j]) ? x : xsel[j];
        }
    }

    // ---------- per-pixel epilogue -> LDS bins ----------
    float vcnt = 0.0f;
#pragma unroll
    for (int j = 0; j < PPT; ++j) {
        const float lse = __logf(se[j]);         // ln(sum exp)
        if (rl[j] != IGN) {
            const int   lab  = (rl[j] >= PASTC) ? rl[j] : arg15[j];  // [0,19]
            const float sval = (rl[j] >= PASTC) ? xsel[j] : x_m15[j];
            const float prob = __expf(sval - lse);
            atomicAdd(&s_acc[lab], prob);
            atomicAdd(&s_acc[20 + lab], 1.0f);
        }
        const int  el    = (rl[j] >= PASTC) ? rl[j] : earg[j];  // 255 stays 255
        const float th   = s_thr[el < NCC ? el : (NCC - 1)];
        const bool valid = (el < NCC) && (esel[j] >= th);
        if (valid) {
            atomicAdd(&s_acc[40 + el], lse - xsel[j]);
        }
        const unsigned long long bm = __ballot(valid);
        if ((tid & 63) == 0) vcnt += (float)__popcll(bm);
    }
    if ((tid & 63) == 0) atomicAdd(&s_acc[60], vcnt);

    __syncthreads();
    if (tid < 61) atomicAdd(&ws[tid], s_acc[tid]);
}

__global__ void dl_final(const float* __restrict__ ws,
                         const float* __restrict__ mpa,
                         float*       __restrict__ out)
{
    if (threadIdx.x == 0 && blockIdx.x == 0) {
        float acc = 0.0f;
        for (int c = 0; c < NCC; ++c) {
            const float ssum = ws[c];
            const float cnt  = ws[20 + c];
            const float lsum = ws[40 + c];
            const float m    = mpa[c];
            const float mean = ssum / fmaxf(cnt, 1.0f);
            const float nm   = (cnt > 0.0f)
                                 ? ((m == -1.0f) ? mean
                                                 : (1.0f - ALPHAF) * mean + ALPHAF * m)
                                 : m;
            acc += lsum * (1.0f - nm);
        }
        out[0] = acc / ws[60];
    }
}

extern "C" void kernel_launch(void* const* d_in, const int* in_sizes, int n_in,
                              void* d_out, int out_size, void* d_ws, size_t ws_size,
                              hipStream_t stream) {
    const float* logit  = (const float*)d_in[0];
    const float* ema    = (const float*)d_in[1];
    const float* thresh = (const float*)d_in[2];
    const int*   real   = (const int*)d_in[3];
    const float* mpa    = (const float*)d_in[4];
    float* out = (float*)d_out;
    float* ws  = (float*)d_ws;

    // ws is re-poisoned to 0xAA before every timed launch; zero the 61 bins.
    hipMemsetAsync(ws, 0, 64 * sizeof(float), stream);

    // 2,097,152 pixels / 16 per thread / 256 per block = 512 blocks (exact)
    dl_main<<<512, 256, 0, stream>>>(logit, ema, thresh, real, ws);
    dl_final<<<1, 64, 0, stream>>>(ws, mpa, out);
}